// Round 10
// baseline (175.934 us; speedup 1.0000x reference)
//
#include <hip/hip_runtime.h>
#include <stdint.h>

typedef __attribute__((ext_vector_type(8))) short bf16x8;
typedef __attribute__((ext_vector_type(4))) float f32x4;

__device__ __forceinline__ uint16_t f2bf(float f) {
  union { float f; uint32_t u; } a; a.f = f;
  uint32_t u = a.u;
  u += 0x7FFFu + ((u >> 16) & 1u);   // RTNE
  return (uint16_t)(u >> 16);
}

__device__ __forceinline__ uint32_t pk_bf16(float a, float b) {
#if __has_builtin(__builtin_amdgcn_cvt_pk_bf16_f32)
  auto r = __builtin_amdgcn_cvt_pk_bf16_f32(a, b);
  uint32_t u; __builtin_memcpy(&u, &r, sizeof(u));
  return u;
#else
  return (uint32_t)f2bf(a) | ((uint32_t)f2bf(b) << 16);
#endif
}

__device__ __forceinline__ uint32_t pk_bf16_fast(float a, float b) {
#if __has_builtin(__builtin_amdgcn_cvt_pk_bf16_f32)
  auto r = __builtin_amdgcn_cvt_pk_bf16_f32(a, b);
  uint32_t u; __builtin_memcpy(&u, &r, sizeof(u));
  return u;
#else
  uint32_t ua, ub;
  __builtin_memcpy(&ua, &a, 4); __builtin_memcpy(&ub, &b, 4);
  return __builtin_amdgcn_perm(ub, ua, 0x07060302u);
#endif
}

__device__ __forceinline__ float fast_exp2(float x) {
#if __has_builtin(__builtin_amdgcn_exp2f)
  return __builtin_amdgcn_exp2f(x);
#else
  return exp2f(x);
#endif
}

__device__ __forceinline__ void gld_lds16(const uint16_t* g, uint16_t* l) {
  __builtin_amdgcn_global_load_lds(
      (const __attribute__((address_space(1))) void*)g,
      (__attribute__((address_space(3))) void*)l, 16, 0, 0);
}

// ---------------- fused cast fp32 -> bf16 ----------------
__global__ void cast_all(const float* __restrict__ x, const float* __restrict__ wq,
                         const float* __restrict__ wk, const float* __restrict__ wv,
                         const float* __restrict__ wff,
                         uint16_t* __restrict__ xb, uint16_t* __restrict__ wqb,
                         uint16_t* __restrict__ wkb, uint16_t* __restrict__ wvb,
                         uint16_t* __restrict__ wffb) {
  int i = blockIdx.x * blockDim.x + threadIdx.x;
  const float* src; uint16_t* dst; int off;
  if (i < 1048576)      { src = x;   dst = xb;   off = i; }
  else if (i < 1310720) { src = wq;  dst = wqb;  off = i - 1048576; }
  else if (i < 1572864) { src = wk;  dst = wkb;  off = i - 1310720; }
  else if (i < 1835008) { src = wv;  dst = wvb;  off = i - 1572864; }
  else                  { src = wff; dst = wffb; off = i - 1835008; }
  float4 v = ((const float4*)src)[off];
  uint2 o; o.x = pk_bf16(v.x, v.y); o.y = pk_bf16(v.z, v.w);
  ((uint2*)dst)[off] = o;
}

// ---------------- shared GEMM mainloop (R5, proven) ----------------
__device__ __forceinline__ void gemm_tile(const uint16_t* __restrict__ Abase,
                                          const uint16_t* __restrict__ Bbase,
                                          uint16_t* lds, f32x4 acc[4][4]) {
  const int tid  = threadIdx.x;
  const int w    = tid >> 6;
  const int lane = tid & 63;
  const int wm   = w >> 1, wn = w & 1;
  const int lrow = lane & 15;
  const int quad = lane >> 4;
  const int srow = lane >> 3;
  const int lc   = (lane & 7) ^ srow;
  const int sx   = lrow & 7;
  uint16_t* a_lds = lds;
  uint16_t* b_lds = lds + 8192;

#pragma unroll
  for (int mt = 0; mt < 4; ++mt)
#pragma unroll
    for (int nt = 0; nt < 4; ++nt)
      acc[mt][nt] = (f32x4){0.f, 0.f, 0.f, 0.f};

  const uint16_t* ag = Abase + (size_t)(w * 32 + srow) * 1024 + lc * 8;
  const uint16_t* bg = Bbase + (size_t)(w * 32 + srow) * 1024 + lc * 8;

  for (int k0 = 0; k0 < 1024; k0 += 64) {
#pragma unroll
    for (int i8 = 0; i8 < 4; ++i8) {
      gld_lds16(ag + (size_t)i8 * 8 * 1024 + k0, a_lds + (w * 4 + i8) * 512);
      gld_lds16(bg + (size_t)i8 * 8 * 1024 + k0, b_lds + (w * 4 + i8) * 512);
    }
    __syncthreads();
#pragma unroll
    for (int ks = 0; ks < 2; ++ks) {
      bf16x8 af[4], bfr[4];
      const int c = ((ks * 4 + quad) ^ sx) << 3;
#pragma unroll
      for (int mt = 0; mt < 4; ++mt)
        af[mt] = *(const bf16x8*)(a_lds + (wm * 64 + mt * 16 + lrow) * 64 + c);
#pragma unroll
      for (int nt = 0; nt < 4; ++nt)
        bfr[nt] = *(const bf16x8*)(b_lds + (wn * 64 + nt * 16 + lrow) * 64 + c);
#pragma unroll
      for (int mt = 0; mt < 4; ++mt)
#pragma unroll
        for (int nt = 0; nt < 4; ++nt)
          acc[mt][nt] = __builtin_amdgcn_mfma_f32_16x16x32_bf16(af[mt], bfr[nt], acc[mt][nt], 0, 0, 0);
    }
    __syncthreads();
  }
}

// ---------------- QKV projection: R5 kernel + XCD-chunked remap (r9, proven) ----------------
__global__ __launch_bounds__(256) void gemm_qkv(
    const uint16_t* __restrict__ x,
    const uint16_t* __restrict__ wq, const uint16_t* __restrict__ wk, const uint16_t* __restrict__ wv,
    uint16_t* __restrict__ qo, uint16_t* __restrict__ ko, uint16_t* __restrict__ vto) {
  __shared__ __align__(16) uint16_t lds[17408];
  const int bx = blockIdx.x;
  const int mi = ((bx & 7) << 2) + (bx >> 3);   // XCD-chunked m-tile
  const int m0 = mi * 128, n0 = blockIdx.y * 128, z = blockIdx.z;
  f32x4 acc[4][4];
  if (z < 2) {
    const uint16_t* W = (z == 0) ? wq : wk;
    gemm_tile(W + (size_t)n0 * 1024, x + (size_t)m0 * 1024, lds, acc);
  } else {
    gemm_tile(x + (size_t)m0 * 1024, wv + (size_t)n0 * 1024, lds, acc);
  }

  const int tid = threadIdx.x;
  const int lane = tid & 63, w = tid >> 6;
  const int wm = w >> 1, wn = w & 1, lrow = lane & 15, quad = lane >> 4;
  const float scale = (z == 0) ? 0.045084222f : 1.0f;  // fold log2(e)/sqrt(1024) into Q

#pragma unroll
  for (int mt = 0; mt < 4; ++mt)
#pragma unroll
    for (int nt = 0; nt < 4; ++nt) {
      int i0 = wm * 64 + mt * 16 + quad * 4;
      int j  = wn * 64 + nt * 16 + lrow;
      uint2 dd;
      dd.x = pk_bf16(acc[mt][nt][0] * scale, acc[mt][nt][1] * scale);
      dd.y = pk_bf16(acc[mt][nt][2] * scale, acc[mt][nt][3] * scale);
      *(uint2*)(&lds[j * 136 + i0]) = dd;
    }
  __syncthreads();

  uint16_t* outp = (z == 0) ? qo : (z == 1) ? ko : vto;
  if (z < 2) {
#pragma unroll
    for (int it = 0; it < 8; ++it) {
      int idx = it * 256 + tid;
      int jj = idx >> 4, cc = idx & 15;
      uint4 v = *(const uint4*)(&lds[jj * 136 + cc * 8]);
      int m = m0 + jj, n = n0 + cc * 8;
      int b = m >> 11, s = m & 2047, h = n >> 6, dh = n & 63;
      *(uint4*)(outp + ((size_t)((b * 16 + h) * 2048 + s)) * 64 + dh) = v;
    }
  } else {
    int b = m0 >> 11, sbase = m0 & 2047;
#pragma unroll
    for (int it = 0; it < 8; ++it) {
      int idx = it * 256 + tid;
      int ff = idx >> 4, cc = idx & 15;
      uint4 v = *(const uint4*)(&lds[ff * 136 + cc * 8]);
      int n = n0 + ff, h = n >> 6, dh = n & 63;
      *(uint4*)(outp + ((size_t)((b * 16 + h) * 64 + dh)) * 2048 + sbase + cc * 8) = v;
    }
  }
}

// ---------------- FF: 128x64 tiles + XCD-chunked remap (r9, proven) ----------------
__global__ __launch_bounds__(256) void gemm_ff(
    const uint16_t* __restrict__ ao, const uint16_t* __restrict__ wff,
    const float* __restrict__ bff, float* __restrict__ out) {
  __shared__ __align__(16) uint16_t lds[12288];   // A 64x64 (4096) + B 128x64 (8192)
  const int bx = blockIdx.x;
  const int mi = ((bx & 7) << 2) + (bx >> 3);   // XCD-chunked m-tile
  const int m0 = mi * 128, n0 = blockIdx.y * 64;
  const int tid  = threadIdx.x;
  const int w    = tid >> 6;
  const int lane = tid & 63;
  const int wm   = w >> 1, wn = w & 1;
  const int lrow = lane & 15;
  const int quad = lane >> 4;
  const int srow = lane >> 3;
  const int lc   = (lane & 7) ^ srow;
  const int sx   = lrow & 7;
  uint16_t* a_lds = lds;           // wff tile: 64 rows (n)
  uint16_t* b_lds = lds + 4096;    // ao tile: 128 rows (m)

  f32x4 acc[4][2];
#pragma unroll
  for (int mt = 0; mt < 4; ++mt)
#pragma unroll
    for (int nt = 0; nt < 2; ++nt)
      acc[mt][nt] = (f32x4){0.f, 0.f, 0.f, 0.f};

  const uint16_t* ag = wff + (size_t)(n0 + w * 16 + srow) * 1024 + lc * 8;
  const uint16_t* bg = ao  + (size_t)(m0 + w * 32 + srow) * 1024 + lc * 8;

  for (int k0 = 0; k0 < 1024; k0 += 64) {
#pragma unroll
    for (int i2 = 0; i2 < 2; ++i2)
      gld_lds16(ag + (size_t)i2 * 8 * 1024 + k0, a_lds + (w * 2 + i2) * 512);
#pragma unroll
    for (int i8 = 0; i8 < 4; ++i8)
      gld_lds16(bg + (size_t)i8 * 8 * 1024 + k0, b_lds + (w * 4 + i8) * 512);
    __syncthreads();
#pragma unroll
    for (int ks = 0; ks < 2; ++ks) {
      bf16x8 af[2], bfr[4];
      const int c = ((ks * 4 + quad) ^ sx) << 3;
#pragma unroll
      for (int nt = 0; nt < 2; ++nt)
        af[nt] = *(const bf16x8*)(a_lds + (wn * 32 + nt * 16 + lrow) * 64 + c);
#pragma unroll
      for (int mt = 0; mt < 4; ++mt)
        bfr[mt] = *(const bf16x8*)(b_lds + (wm * 64 + mt * 16 + lrow) * 64 + c);
#pragma unroll
      for (int mt = 0; mt < 4; ++mt)
#pragma unroll
        for (int nt = 0; nt < 2; ++nt)
          acc[mt][nt] = __builtin_amdgcn_mfma_f32_16x16x32_bf16(af[nt], bfr[mt], acc[mt][nt], 0, 0, 0);
    }
    __syncthreads();
  }

  float* fl = (float*)lds;
#pragma unroll
  for (int p = 0; p < 2; ++p) {
    if (wm == p) {
#pragma unroll
      for (int mt = 0; mt < 4; ++mt)
#pragma unroll
        for (int nt = 0; nt < 2; ++nt)
          *(f32x4*)(&fl[(mt * 16 + lrow) * 68 + wn * 32 + nt * 16 + quad * 4]) = acc[mt][nt];
    }
    __syncthreads();
#pragma unroll
    for (int it = 0; it < 4; ++it) {
      int idx = it * 256 + tid;
      int jj = idx >> 4, cc = idx & 15;
      f32x4 v = *(const f32x4*)(&fl[jj * 68 + cc * 4]);
      int n = n0 + cc * 4;
      f32x4 bias = *(const f32x4*)(bff + n);
      f32x4 vv = v + bias;
      *(f32x4*)(out + (size_t)(m0 + p * 64 + jj) * 1024 + n) = vv;
    }
    __syncthreads();
  }
}

// ---------------- flash attention: KVBLK=32, 40 KB LDS -> 3 blocks/CU target ----------------
// Round-10 change: halve the K-block (64->32 keys/iter, 64 iters). Unlike r1 (which halved
// MFMA but kept staging constant), ALL per-iter costs halve together: staged B/MFMA (128),
// LDS-ops/MFMA, exp2/MFMA preserved. LDS 64->40 KB (K 2x4KB dbuf; V one 64-key tile staged
// half-per-iter into a dbuf; P [128 qrow][32 key] 2x8KB). Per-wave state halves -> ~70 VGPR
// -> launch_bounds(512,6) caps at 85 -> 3 blocks/CU = 24 waves (falsifier: WRITE_SIZE jump
// = spill). PV k=32 covers ALL keys of the block -> every O element single-owner: the
// cross-wave arena combine + its barriers are GONE from the epilogue.
// Roles: S^T wave (kt=w&1: keys kt*16..+16; qg=w>>1: qrows qg*32..+32).
//        PV  wave (dh half kt*32..+32; same qrows qg*32..+32).
// P-row = 64B: write slot (4 elems) = (kt*4+quad)^(lrow&6)  [even swizzle keeps the 16B read
// chunk aligned AND key-order correct]; read chunk (8 elems) = quad^((row>>1)&3). Both <=2-way
// per 16-lane phase (free). K rows stay 128B with the proven ^sx swizzle; V tile unchanged
// from r9 (64-key rows, ^sx), block parity selects the chunk half: (kb&1)*4+quad.
__global__ __launch_bounds__(512, 6) void attn(
    const uint16_t* __restrict__ q, const uint16_t* __restrict__ k,
    const uint16_t* __restrict__ vt, uint16_t* __restrict__ ao) {
  __shared__ __align__(16) uint16_t lds_all[20480];   // 40 KB
  uint16_t* const k_lds = lds_all;            // [2][2048]: [buf][key 32][dh 64], ^sx swizzled
  uint16_t* const v_lds = lds_all + 4096;     // [2][4096]: [buf][dh 64][key 64], ^sx swizzled
  uint16_t* const p_lds = lds_all + 12288;    // [2][4096]: [buf][qrow 128][key 32], swizzled
  const int tid = threadIdx.x, w = tid >> 6, lane = tid & 63;
  const int lrow = lane & 15, quad = lane >> 4;
  const int srow = lane >> 3, lc = (lane & 7) ^ srow, sx = lrow & 7;
  const int kt = w & 1, qg = w >> 1;   // kt: key-16-half / dh-32-half; qg: qrow-32-group

  // XCD-aware bijective swizzle (r8, proven): 64 consecutive logical blocks per XCD
  const int lin = blockIdx.x + (blockIdx.y << 4);          // 0..511
  const int wl  = ((lin & 7) << 6) + (lin >> 3);           // bijective remap
  const int qb  = wl & 15, bh = wl >> 4;

  const uint16_t* Q = q  + (size_t)bh * (2048 * 64);
  const uint16_t* K = k  + (size_t)bh * (2048 * 64);
  const uint16_t* V = vt + (size_t)bh * (64 * 2048);

  const int qr0 = qb * 128;
  bf16x8 qf[2][2];   // [qh][ks]: B-frag, qrow = qr0 + qg*32 + qh*16 + lrow (scale pre-folded)
#pragma unroll
  for (int qh = 0; qh < 2; ++qh)
#pragma unroll
    for (int ks = 0; ks < 2; ++ks)
      qf[qh][ks] = *(const bf16x8*)(Q + (size_t)(qr0 + qg * 32 + qh * 16 + lrow) * 64 + ks * 32 + quad * 8);

  f32x4 o[2][2];     // [qh][dtl]: dh = kt*32 + dtl*16 + quad*4 + r, qrow = qg*32 + qh*16 + lrow
#pragma unroll
  for (int qh = 0; qh < 2; ++qh)
#pragma unroll
    for (int dtl = 0; dtl < 2; ++dtl) o[qh][dtl] = (f32x4){0.f, 0.f, 0.f, 0.f};
  float ls[2] = {0.f, 0.f};
  bf16x8 vfr[2];     // V(kb) A-frags for dh half kt, carried to iter kb+1

  // K(kb1): 4KB tile, waves 0-3 stage rows w*8+srow (32 key-rows x 64 dh)
  // V tile j (keys j*64..+64): 8KB, 8 segs; seg = dh rows seg*8+srow x 64 keys
  if (w < 4)
    gld_lds16(K + (size_t)(0 * 32 + w * 8 + srow) * 64 + lc * 8, k_lds + 0 * 2048 + w * 512);
  gld_lds16(V + (size_t)(w * 8 + srow) * 2048 + 0 * 64 + lc * 8, v_lds + 0 * 4096 + w * 512);

  for (int kb = 0; kb < 64; ++kb) {
    const int pb   = kb & 1;          // P buf written this iter
    const int vb   = (kb >> 1) & 1;   // V buf consumed
    const int kbuf = kb & 1;          // K buf consumed
    __syncthreads();   // staging drained; P(kb-1) visible; prev-iter LDS reads done

    // stage early: K(kb+1) by waves 0-3; V half (kb&1) of next 64-key tile by waves 4-7
    if (kb + 1 < 64 && w < 4)
      gld_lds16(K + (size_t)((kb + 1) * 32 + w * 8 + srow) * 64 + lc * 8,
                k_lds + ((kb + 1) & 1) * 2048 + w * 512);
    {
      const int vtile = (kb >> 1) + 1;
      if (vtile < 32 && w >= 4) {
        const int seg = (kb & 1) * 4 + (w - 4);
        gld_lds16(V + (size_t)(seg * 8 + srow) * 2048 + vtile * 64 + lc * 8,
                  v_lds + (vtile & 1) * 4096 + seg * 512);
      }
    }

    if (kb > 0) {
      // PV(kb-1): O += V^T(kb-1) * P^T(kb-1); V in regs, P from p_lds[pb^1]
      const uint16_t* pbuf = p_lds + (pb ^ 1) * 4096;
      __builtin_amdgcn_s_setprio(1);
#pragma unroll
      for (int qh = 0; qh < 2; ++qh) {
        int row = qg * 32 + qh * 16 + lrow;
        bf16x8 pa = *(const bf16x8*)(pbuf + row * 32 + ((quad ^ ((row >> 1) & 3)) << 3));
#pragma unroll
        for (int dtl = 0; dtl < 2; ++dtl)
          o[qh][dtl] = __builtin_amdgcn_mfma_f32_16x16x32_bf16(vfr[dtl], pa, o[qh][dtl], 0, 0, 0);
      }
      __builtin_amdgcn_s_setprio(0);
    }

    // vfr(kb): V^T[kt*32 + dtl*16 + lrow][keys (kb&1)*32 + quad*8 ..+8] from v_lds[vb]
#pragma unroll
    for (int dtl = 0; dtl < 2; ++dtl)
      vfr[dtl] = *(const bf16x8*)(v_lds + vb * 4096 + (kt * 32 + dtl * 16 + lrow) * 64
                                  + ((((kb & 1) * 4 + quad) ^ sx) << 3));

    // S^T(kb): keys kt*16..+16 x qrows qg*32..+32; s[qh]: key = kt*16+quad*4+r, qrow = ..+lrow
    f32x4 s[2];
#pragma unroll
    for (int qh = 0; qh < 2; ++qh) s[qh] = (f32x4){0.f, 0.f, 0.f, 0.f};
    __builtin_amdgcn_s_setprio(1);
#pragma unroll
    for (int ks = 0; ks < 2; ++ks) {
      bf16x8 kf = *(const bf16x8*)(k_lds + kbuf * 2048 + (kt * 16 + lrow) * 64 + (((ks * 4 + quad) ^ sx) << 3));
#pragma unroll
      for (int qh = 0; qh < 2; ++qh)
        s[qh] = __builtin_amdgcn_mfma_f32_16x16x32_bf16(kf, qf[qh][ks], s[qh], 0, 0, 0);
    }
    __builtin_amdgcn_s_setprio(0);

    // exp2 + l partials + P(kb) write: slot (4 elems) = (kt*4+quad)^(lrow&6)
    uint16_t* pbw = p_lds + pb * 4096;
#pragma unroll
    for (int qh = 0; qh < 2; ++qh) {
      float p0 = fast_exp2(s[qh][0]);
      float p1 = fast_exp2(s[qh][1]);
      float p2 = fast_exp2(s[qh][2]);
      float p3 = fast_exp2(s[qh][3]);
      ls[qh] += (p0 + p1) + (p2 + p3);
      uint2 dd; dd.x = pk_bf16_fast(p0, p1); dd.y = pk_bf16_fast(p2, p3);
      int row = qg * 32 + qh * 16 + lrow;
      *(uint2*)(pbw + row * 32 + (((kt * 4 + quad) ^ (lrow & 6)) << 2)) = dd;
    }
  }

  // final PV(63): P in p_lds[1], V(63) in registers
  __syncthreads();   // P(63) visible
  {
    const uint16_t* pbuf = p_lds + 4096;
    __builtin_amdgcn_s_setprio(1);
#pragma unroll
    for (int qh = 0; qh < 2; ++qh) {
      int row = qg * 32 + qh * 16 + lrow;
      bf16x8 pa = *(const bf16x8*)(pbuf + row * 32 + ((quad ^ ((row >> 1) & 3)) << 3));
#pragma unroll
      for (int dtl = 0; dtl < 2; ++dtl)
        o[qh][dtl] = __builtin_amdgcn_mfma_f32_16x16x32_bf16(vfr[dtl], pa, o[qh][dtl], 0, 0, 0);
    }
    __builtin_amdgcn_s_setprio(0);
  }
  __syncthreads();   // final PV reads done before LDS is reused

  // l: quad-reduce -> lane holds this wave's 16-key-half sum for qrow qg*32+qh*16+lrow
#pragma unroll
  for (int qh = 0; qh < 2; ++qh) {
    ls[qh] += __shfl_xor(ls[qh], 16);
    ls[qh] += __shfl_xor(ls[qh], 32);
  }
  float* lred = (float*)lds_all;   // [kt 2][qrow 128] fp32 = 1 KB (overlays k_lds; reads done)
  if (quad == 0) {
#pragma unroll
    for (int qh = 0; qh < 2; ++qh) lred[kt * 128 + qg * 32 + qh * 16 + lrow] = ls[qh];
  }
  __syncthreads();

  // output: each wave owns qrows qg*32..+32 x dh kt*32..+32 (single-owner, no combine)
  {
    const int b = bh >> 4, h = bh & 15;
#pragma unroll
    for (int qh = 0; qh < 2; ++qh) {
      int row = qg * 32 + qh * 16 + lrow;   // block-relative qrow
      float l = lred[row] + lred[128 + row];
      float inv = 1.0f / l;
      int sg = qr0 + row;
#pragma unroll
      for (int dtl = 0; dtl < 2; ++dtl) {
        uint2 dd;
        dd.x = pk_bf16(o[qh][dtl][0] * inv, o[qh][dtl][1] * inv);
        dd.y = pk_bf16(o[qh][dtl][2] * inv, o[qh][dtl][3] * inv);
        *(uint2*)(ao + (size_t)(b * 2048 + sg) * 1024 + h * 64 + kt * 32 + dtl * 16 + quad * 4) = dd;
      }
    }
  }
}

extern "C" void kernel_launch(void* const* d_in, const int* in_sizes, int n_in,
                              void* d_out, int out_size, void* d_ws, size_t ws_size,
                              hipStream_t stream) {
  const float* x   = (const float*)d_in[0];
  const float* Wq  = (const float*)d_in[1];
  const float* Wk  = (const float*)d_in[2];
  const float* Wv  = (const float*)d_in[3];
  const float* Wff = (const float*)d_in[4];
  const float* bff = (const float*)d_in[5];
  float* out = (float*)d_out;

  uint16_t* ws = (uint16_t*)d_ws;
  uint16_t* x_bf   = ws;                 // 4M elems
  uint16_t* wq_bf  = ws + 4194304;       // 1M
  uint16_t* wk_bf  = ws + 5242880;       // 1M
  uint16_t* wv_bf  = ws + 6291456;       // 1M
  uint16_t* wff_bf = ws + 7340032;       // 1M
  uint16_t* q_bf   = ws + 8388608;       // 4M  (b,h,s,dh), pre-scaled by log2e/sqrt(D)
  uint16_t* k_bf   = ws + 12582912;      // 4M  (b,h,s,dh)
  uint16_t* vt_bf  = ws + 16777216;      // 4M  (b,h,dh,s)
  uint16_t* ao_bf  = ws + 20971520;      // 4M  (b,s,h*64+dh)

  cast_all<<<8192, 256, 0, stream>>>(x, Wq, Wk, Wv, Wff, x_bf, wq_bf, wk_bf, wv_bf, wff_bf);

  gemm_qkv<<<dim3(32, 8, 3), 256, 0, stream>>>(x_bf, wq_bf, wk_bf, wv_bf, q_bf, k_bf, vt_bf);
  attn<<<dim3(16, 32), 512, 0, stream>>>(q_bf, k_bf, vt_bf, ao_bf);
  gemm_ff<<<dim3(32, 16), 256, 0, stream>>>(ao_bf, wff_bf, bff, out);
}

// Round 11
// 172.532 us; speedup vs baseline: 1.0197x; 1.0197x over previous
//
#include <hip/hip_runtime.h>
#include <stdint.h>

typedef __attribute__((ext_vector_type(8))) short bf16x8;
typedef __attribute__((ext_vector_type(4))) float f32x4;

__device__ __forceinline__ uint16_t f2bf(float f) {
  union { float f; uint32_t u; } a; a.f = f;
  uint32_t u = a.u;
  u += 0x7FFFu + ((u >> 16) & 1u);   // RTNE
  return (uint16_t)(u >> 16);
}

__device__ __forceinline__ uint32_t pk_bf16(float a, float b) {
#if __has_builtin(__builtin_amdgcn_cvt_pk_bf16_f32)
  auto r = __builtin_amdgcn_cvt_pk_bf16_f32(a, b);
  uint32_t u; __builtin_memcpy(&u, &r, sizeof(u));
  return u;
#else
  return (uint32_t)f2bf(a) | ((uint32_t)f2bf(b) << 16);
#endif
}

__device__ __forceinline__ uint32_t pk_bf16_fast(float a, float b) {
#if __has_builtin(__builtin_amdgcn_cvt_pk_bf16_f32)
  auto r = __builtin_amdgcn_cvt_pk_bf16_f32(a, b);
  uint32_t u; __builtin_memcpy(&u, &r, sizeof(u));
  return u;
#else
  uint32_t ua, ub;
  __builtin_memcpy(&ua, &a, 4); __builtin_memcpy(&ub, &b, 4);
  return __builtin_amdgcn_perm(ub, ua, 0x07060302u);
#endif
}

__device__ __forceinline__ float fast_exp2(float x) {
#if __has_builtin(__builtin_amdgcn_exp2f)
  return __builtin_amdgcn_exp2f(x);
#else
  return exp2f(x);
#endif
}

__device__ __forceinline__ void gld_lds16(const uint16_t* g, uint16_t* l) {
  __builtin_amdgcn_global_load_lds(
      (const __attribute__((address_space(1))) void*)g,
      (__attribute__((address_space(3))) void*)l, 16, 0, 0);
}

// ---------------- fused cast fp32 -> bf16 ----------------
__global__ void cast_all(const float* __restrict__ x, const float* __restrict__ wq,
                         const float* __restrict__ wk, const float* __restrict__ wv,
                         const float* __restrict__ wff,
                         uint16_t* __restrict__ xb, uint16_t* __restrict__ wqb,
                         uint16_t* __restrict__ wkb, uint16_t* __restrict__ wvb,
                         uint16_t* __restrict__ wffb) {
  int i = blockIdx.x * blockDim.x + threadIdx.x;
  const float* src; uint16_t* dst; int off;
  if (i < 1048576)      { src = x;   dst = xb;   off = i; }
  else if (i < 1310720) { src = wq;  dst = wqb;  off = i - 1048576; }
  else if (i < 1572864) { src = wk;  dst = wkb;  off = i - 1310720; }
  else if (i < 1835008) { src = wv;  dst = wvb;  off = i - 1572864; }
  else                  { src = wff; dst = wffb; off = i - 1835008; }
  float4 v = ((const float4*)src)[off];
  uint2 o; o.x = pk_bf16(v.x, v.y); o.y = pk_bf16(v.z, v.w);
  ((uint2*)dst)[off] = o;
}

// ---------------- shared GEMM mainloop (R5, proven) ----------------
__device__ __forceinline__ void gemm_tile(const uint16_t* __restrict__ Abase,
                                          const uint16_t* __restrict__ Bbase,
                                          uint16_t* lds, f32x4 acc[4][4]) {
  const int tid  = threadIdx.x;
  const int w    = tid >> 6;
  const int lane = tid & 63;
  const int wm   = w >> 1, wn = w & 1;
  const int lrow = lane & 15;
  const int quad = lane >> 4;
  const int srow = lane >> 3;
  const int lc   = (lane & 7) ^ srow;
  const int sx   = lrow & 7;
  uint16_t* a_lds = lds;
  uint16_t* b_lds = lds + 8192;

#pragma unroll
  for (int mt = 0; mt < 4; ++mt)
#pragma unroll
    for (int nt = 0; nt < 4; ++nt)
      acc[mt][nt] = (f32x4){0.f, 0.f, 0.f, 0.f};

  const uint16_t* ag = Abase + (size_t)(w * 32 + srow) * 1024 + lc * 8;
  const uint16_t* bg = Bbase + (size_t)(w * 32 + srow) * 1024 + lc * 8;

  for (int k0 = 0; k0 < 1024; k0 += 64) {
#pragma unroll
    for (int i8 = 0; i8 < 4; ++i8) {
      gld_lds16(ag + (size_t)i8 * 8 * 1024 + k0, a_lds + (w * 4 + i8) * 512);
      gld_lds16(bg + (size_t)i8 * 8 * 1024 + k0, b_lds + (w * 4 + i8) * 512);
    }
    __syncthreads();
#pragma unroll
    for (int ks = 0; ks < 2; ++ks) {
      bf16x8 af[4], bfr[4];
      const int c = ((ks * 4 + quad) ^ sx) << 3;
#pragma unroll
      for (int mt = 0; mt < 4; ++mt)
        af[mt] = *(const bf16x8*)(a_lds + (wm * 64 + mt * 16 + lrow) * 64 + c);
#pragma unroll
      for (int nt = 0; nt < 4; ++nt)
        bfr[nt] = *(const bf16x8*)(b_lds + (wn * 64 + nt * 16 + lrow) * 64 + c);
#pragma unroll
      for (int mt = 0; mt < 4; ++mt)
#pragma unroll
        for (int nt = 0; nt < 4; ++nt)
          acc[mt][nt] = __builtin_amdgcn_mfma_f32_16x16x32_bf16(af[mt], bfr[nt], acc[mt][nt], 0, 0, 0);
    }
    __syncthreads();
  }
}

// ---------------- QKV projection: R5 kernel + XCD-chunked remap (r9, proven) ----------------
__global__ __launch_bounds__(256) void gemm_qkv(
    const uint16_t* __restrict__ x,
    const uint16_t* __restrict__ wq, const uint16_t* __restrict__ wk, const uint16_t* __restrict__ wv,
    uint16_t* __restrict__ qo, uint16_t* __restrict__ ko, uint16_t* __restrict__ vto) {
  __shared__ __align__(16) uint16_t lds[17408];
  const int bx = blockIdx.x;
  const int mi = ((bx & 7) << 2) + (bx >> 3);   // XCD-chunked m-tile
  const int m0 = mi * 128, n0 = blockIdx.y * 128, z = blockIdx.z;
  f32x4 acc[4][4];
  if (z < 2) {
    const uint16_t* W = (z == 0) ? wq : wk;
    gemm_tile(W + (size_t)n0 * 1024, x + (size_t)m0 * 1024, lds, acc);
  } else {
    gemm_tile(x + (size_t)m0 * 1024, wv + (size_t)n0 * 1024, lds, acc);
  }

  const int tid = threadIdx.x;
  const int lane = tid & 63, w = tid >> 6;
  const int wm = w >> 1, wn = w & 1, lrow = lane & 15, quad = lane >> 4;
  const float scale = (z == 0) ? 0.045084222f : 1.0f;  // fold log2(e)/sqrt(1024) into Q

#pragma unroll
  for (int mt = 0; mt < 4; ++mt)
#pragma unroll
    for (int nt = 0; nt < 4; ++nt) {
      int i0 = wm * 64 + mt * 16 + quad * 4;
      int j  = wn * 64 + nt * 16 + lrow;
      uint2 dd;
      dd.x = pk_bf16(acc[mt][nt][0] * scale, acc[mt][nt][1] * scale);
      dd.y = pk_bf16(acc[mt][nt][2] * scale, acc[mt][nt][3] * scale);
      *(uint2*)(&lds[j * 136 + i0]) = dd;
    }
  __syncthreads();

  uint16_t* outp = (z == 0) ? qo : (z == 1) ? ko : vto;
  if (z < 2) {
#pragma unroll
    for (int it = 0; it < 8; ++it) {
      int idx = it * 256 + tid;
      int jj = idx >> 4, cc = idx & 15;
      uint4 v = *(const uint4*)(&lds[jj * 136 + cc * 8]);
      int m = m0 + jj, n = n0 + cc * 8;
      int b = m >> 11, s = m & 2047, h = n >> 6, dh = n & 63;
      *(uint4*)(outp + ((size_t)((b * 16 + h) * 2048 + s)) * 64 + dh) = v;
    }
  } else {
    int b = m0 >> 11, sbase = m0 & 2047;
#pragma unroll
    for (int it = 0; it < 8; ++it) {
      int idx = it * 256 + tid;
      int ff = idx >> 4, cc = idx & 15;
      uint4 v = *(const uint4*)(&lds[ff * 136 + cc * 8]);
      int n = n0 + ff, h = n >> 6, dh = n & 63;
      *(uint4*)(outp + ((size_t)((b * 16 + h) * 64 + dh)) * 2048 + sbase + cc * 8) = v;
    }
  }
}

// ---------------- FF: 128x64 tiles + XCD-chunked remap (r9, proven) ----------------
__global__ __launch_bounds__(256) void gemm_ff(
    const uint16_t* __restrict__ ao, const uint16_t* __restrict__ wff,
    const float* __restrict__ bff, float* __restrict__ out) {
  __shared__ __align__(16) uint16_t lds[12288];   // A 64x64 (4096) + B 128x64 (8192)
  const int bx = blockIdx.x;
  const int mi = ((bx & 7) << 2) + (bx >> 3);   // XCD-chunked m-tile
  const int m0 = mi * 128, n0 = blockIdx.y * 64;
  const int tid  = threadIdx.x;
  const int w    = tid >> 6;
  const int lane = tid & 63;
  const int wm   = w >> 1, wn = w & 1;
  const int lrow = lane & 15;
  const int quad = lane >> 4;
  const int srow = lane >> 3;
  const int lc   = (lane & 7) ^ srow;
  const int sx   = lrow & 7;
  uint16_t* a_lds = lds;           // wff tile: 64 rows (n)
  uint16_t* b_lds = lds + 4096;    // ao tile: 128 rows (m)

  f32x4 acc[4][2];
#pragma unroll
  for (int mt = 0; mt < 4; ++mt)
#pragma unroll
    for (int nt = 0; nt < 2; ++nt)
      acc[mt][nt] = (f32x4){0.f, 0.f, 0.f, 0.f};

  const uint16_t* ag = wff + (size_t)(n0 + w * 16 + srow) * 1024 + lc * 8;
  const uint16_t* bg = ao  + (size_t)(m0 + w * 32 + srow) * 1024 + lc * 8;

  for (int k0 = 0; k0 < 1024; k0 += 64) {
#pragma unroll
    for (int i2 = 0; i2 < 2; ++i2)
      gld_lds16(ag + (size_t)i2 * 8 * 1024 + k0, a_lds + (w * 2 + i2) * 512);
#pragma unroll
    for (int i8 = 0; i8 < 4; ++i8)
      gld_lds16(bg + (size_t)i8 * 8 * 1024 + k0, b_lds + (w * 4 + i8) * 512);
    __syncthreads();
#pragma unroll
    for (int ks = 0; ks < 2; ++ks) {
      bf16x8 af[2], bfr[4];
      const int c = ((ks * 4 + quad) ^ sx) << 3;
#pragma unroll
      for (int nt = 0; nt < 2; ++nt)
        af[nt] = *(const bf16x8*)(a_lds + (wn * 32 + nt * 16 + lrow) * 64 + c);
#pragma unroll
      for (int mt = 0; mt < 4; ++mt)
        bfr[mt] = *(const bf16x8*)(b_lds + (wm * 64 + mt * 16 + lrow) * 64 + c);
#pragma unroll
      for (int mt = 0; mt < 4; ++mt)
#pragma unroll
        for (int nt = 0; nt < 2; ++nt)
          acc[mt][nt] = __builtin_amdgcn_mfma_f32_16x16x32_bf16(af[nt], bfr[mt], acc[mt][nt], 0, 0, 0);
    }
    __syncthreads();
  }

  float* fl = (float*)lds;
#pragma unroll
  for (int p = 0; p < 2; ++p) {
    if (wm == p) {
#pragma unroll
      for (int mt = 0; mt < 4; ++mt)
#pragma unroll
        for (int nt = 0; nt < 2; ++nt)
          *(f32x4*)(&fl[(mt * 16 + lrow) * 68 + wn * 32 + nt * 16 + quad * 4]) = acc[mt][nt];
    }
    __syncthreads();
#pragma unroll
    for (int it = 0; it < 4; ++it) {
      int idx = it * 256 + tid;
      int jj = idx >> 4, cc = idx & 15;
      f32x4 v = *(const f32x4*)(&fl[jj * 68 + cc * 4]);
      int n = n0 + cc * 4;
      f32x4 bias = *(const f32x4*)(bff + n);
      f32x4 vv = v + bias;
      *(f32x4*)(out + (size_t)(m0 + p * 64 + jj) * 1024 + n) = vv;
    }
    __syncthreads();
  }
}

// ---------------- flash attention: r9 configuration, FINAL (47.5 us measured) ----------------
// Verified local optimum of this decomposition:
//   r4: 8 waves/block (16 waves/CU)           56.9 -> 54.8
//   r5: conflict-free P swizzle (8.7M -> 2.2M) 54.8 -> 48.5
//   r8: XCD swizzle (FETCH 69.7 -> 12.3 MB)    48.5 -> 47.7
// Failed structural probes (all reverted): 64-row tile (r1: staging/MFMA doubled),
// single-P (r2/r3: reg-spill / extra barrier), V-direct-to-reg (r6: TA-pipe 4x dup),
// KVBLK=32 (r10: fixed overhead per iter doubled vs halved MFMA).
// Remaining bound: LDS-mediated cross-wave P exchange (S^T and PV partition key x qrow
// space differently -> LDS is the exchange mechanism; its read/write chain + one barrier
// per 64-key step is the critical path). Not memory-bound (HBM 3-5%), not MFMA-bound (28%).
__global__ __launch_bounds__(512, 4) void attn(
    const uint16_t* __restrict__ q, const uint16_t* __restrict__ k,
    const uint16_t* __restrict__ vt, uint16_t* __restrict__ ao) {
  __shared__ __align__(16) uint16_t lds_all[32768];   // 64 KB
  uint16_t* const k_lds = lds_all;            // [2][4096]: [buf][key 64][dh 64], swizzled
  uint16_t* const v_lds = lds_all + 8192;     // [2][4096]: [buf][dh 64][key 64], swizzled
  uint16_t* const p_lds = lds_all + 16384;    // [2][8192]: [buf][qrow 128][key 64], swizzled
  const int tid = threadIdx.x, w = tid >> 6, lane = tid & 63;
  const int lrow = lane & 15, quad = lane >> 4;
  const int srow = lane >> 3, lc = (lane & 7) ^ srow, sx = lrow & 7;
  const int kw = w & 3, qw = w >> 2;   // S^T role
  const int pk = w & 1, pq = w >> 1;   // PV role
  const int pswz = (lrow & 7) << 1;    // conflict-free P swizzle (r5, proven)

  // XCD-aware bijective swizzle (r8, proven): 64 consecutive logical blocks per XCD
  const int lin = blockIdx.x + (blockIdx.y << 4);          // 0..511
  const int wl  = ((lin & 7) << 6) + (lin >> 3);           // bijective remap
  const int qb  = wl & 15, bh = wl >> 4;

  const uint16_t* Q = q  + (size_t)bh * (2048 * 64);
  const uint16_t* K = k  + (size_t)bh * (2048 * 64);
  const uint16_t* V = vt + (size_t)bh * (64 * 2048);

  const int qr0 = qb * 128;
  bf16x8 qf[4][2];   // [qh 0..3][ks]: B-frag for qrows qw*64 + qh*16 + lrow
#pragma unroll
  for (int qh = 0; qh < 4; ++qh)
#pragma unroll
    for (int ks = 0; ks < 2; ++ks)
      qf[qh][ks] = *(const bf16x8*)(Q + (size_t)(qr0 + qw * 64 + qh * 16 + lrow) * 64 + ks * 32 + quad * 8);

  f32x4 o[2][4];     // O-partial: [qh2 0..1][dt]; dh=dt*16+quad*4+r, qrow=pq*32+qh2*16+lrow, keys pk*32..+32
#pragma unroll
  for (int qh2 = 0; qh2 < 2; ++qh2)
#pragma unroll
    for (int dt = 0; dt < 4; ++dt) o[qh2][dt] = (f32x4){0.f, 0.f, 0.f, 0.f};
  float ls[4] = {0.f, 0.f, 0.f, 0.f};
  bf16x8 vfr[4];     // V(kb) A-fragments for key-half pk, carried to iteration kb+1

  auto stage = [&](int kb, int bi) {
    // 8 waves, one K-row-group + one V-row-group each (i8 = w)
    gld_lds16(K + (size_t)(kb * 64 + w * 8 + srow) * 64 + lc * 8, k_lds + bi * 4096 + w * 512);
    gld_lds16(V + (size_t)(w * 8 + srow) * 2048 + kb * 64 + lc * 8, v_lds + bi * 4096 + w * 512);
  };
  stage(0, 0);

  for (int kb = 0; kb < 32; ++kb) {
    const int bi = kb & 1;
    __syncthreads();   // staging(kb) drained; P(kb-1) visible; prev-iter LDS reads done

    if (kb > 0) {
      // PV(kb-1): O += V^T(kb-1) * P^T(kb-1); V from registers (race-free)
      const uint16_t* pbuf = p_lds + (bi ^ 1) * 8192;
      __builtin_amdgcn_s_setprio(1);
#pragma unroll
      for (int qh2 = 0; qh2 < 2; ++qh2) {
        int row = pq * 32 + qh2 * 16 + lrow;
        bf16x8 pa = *(const bf16x8*)(pbuf + row * 64 + (((pk * 8 + quad * 2) ^ pswz) << 2));
#pragma unroll
        for (int dt = 0; dt < 4; ++dt)
          o[qh2][dt] = __builtin_amdgcn_mfma_f32_16x16x32_bf16(vfr[dt], pa, o[qh2][dt], 0, 0, 0);
      }
      __builtin_amdgcn_s_setprio(0);
    }

    // load V(kb) fragments from v_lds[bi] (stage below writes bi^1 only)
#pragma unroll
    for (int dt = 0; dt < 4; ++dt)
      vfr[dt] = *(const bf16x8*)(v_lds + bi * 4096 + (dt * 16 + lrow) * 64 + (((pk * 4 + quad) ^ sx) << 3));

    if (kb + 1 < 32) stage(kb + 1, bi ^ 1);

    // S^T(kb): keys kw*16..+16 x qrows qw*64..+64; s[qh]: key=kw*16+quad*4+r, qrow=qw*64+qh*16+lrow
    f32x4 s[4];
#pragma unroll
    for (int qh = 0; qh < 4; ++qh) s[qh] = (f32x4){0.f, 0.f, 0.f, 0.f};
    __builtin_amdgcn_s_setprio(1);
#pragma unroll
    for (int ks = 0; ks < 2; ++ks) {
      bf16x8 kf = *(const bf16x8*)(k_lds + bi * 4096 + (kw * 16 + lrow) * 64 + (((ks * 4 + quad) ^ sx) << 3));
#pragma unroll
      for (int qh = 0; qh < 4; ++qh)
        s[qh] = __builtin_amdgcn_mfma_f32_16x16x32_bf16(kf, qf[qh][ks], s[qh], 0, 0, 0);
    }
    __builtin_amdgcn_s_setprio(0);

    // exp2 + l partials + P(kb) write to p_lds[bi]
    uint16_t* pbw = p_lds + bi * 8192;
#pragma unroll
    for (int qh = 0; qh < 4; ++qh) {
      float p0 = fast_exp2(s[qh][0]);
      float p1 = fast_exp2(s[qh][1]);
      float p2 = fast_exp2(s[qh][2]);
      float p3 = fast_exp2(s[qh][3]);
      ls[qh] += (p0 + p1) + (p2 + p3);
      uint2 dd; dd.x = pk_bf16_fast(p0, p1); dd.y = pk_bf16_fast(p2, p3);
      int row = qw * 64 + qh * 16 + lrow;
      *(uint2*)(pbw + row * 64 + (((kw * 4 + quad) ^ pswz) << 2)) = dd;
    }
  }

  // final PV(31): P in p_lds[1], V(31) in registers
  __syncthreads();
  {
    const uint16_t* pbuf = p_lds + 8192;
    __builtin_amdgcn_s_setprio(1);
#pragma unroll
    for (int qh2 = 0; qh2 < 2; ++qh2) {
      int row = pq * 32 + qh2 * 16 + lrow;
      bf16x8 pa = *(const bf16x8*)(pbuf + row * 64 + (((pk * 8 + quad * 2) ^ pswz) << 2));
#pragma unroll
      for (int dt = 0; dt < 4; ++dt)
        o[qh2][dt] = __builtin_amdgcn_mfma_f32_16x16x32_bf16(vfr[dt], pa, o[qh2][dt], 0, 0, 0);
    }
    __builtin_amdgcn_s_setprio(0);
  }
  __syncthreads();   // final PV reads done before LDS is reused below

  // l: quad-reduce -> each lane holds this wave's 16-key sum for qrow qw*64 + qh*16 + lrow
#pragma unroll
  for (int qh = 0; qh < 4; ++qh) {
    ls[qh] += __shfl_xor(ls[qh], 16);
    ls[qh] += __shfl_xor(ls[qh], 32);
  }
  // arena: [qrow 128][dh 64] fp32, STRIDE 68 floats (272B -> bank shift 4/row, conflict-free)
  float* arena = (float*)lds_all;
  float* lred  = (float*)(lds_all + 17408);
  if (quad == 0) {
#pragma unroll
    for (int qh = 0; qh < 4; ++qh) lred[kw * 128 + qw * 64 + qh * 16 + lrow] = ls[qh];
  }
  if (pk == 1) {
#pragma unroll
    for (int qh2 = 0; qh2 < 2; ++qh2)
#pragma unroll
      for (int dt = 0; dt < 4; ++dt)
        *(f32x4*)(&arena[(pq * 32 + qh2 * 16 + lrow) * 68 + dt * 16 + quad * 4]) = o[qh2][dt];
  }
  __syncthreads();

  if (pk == 0) {
    const int b = bh >> 4, h = bh & 15;
#pragma unroll
    for (int qh2 = 0; qh2 < 2; ++qh2) {
      int qrow = pq * 32 + qh2 * 16 + lrow;   // block-relative
      float l = lred[qrow] + lred[128 + qrow] + lred[256 + qrow] + lred[384 + qrow];
      float inv = 1.0f / l;
      int sg = qr0 + qrow;
#pragma unroll
      for (int dt = 0; dt < 4; ++dt) {
        f32x4 a = *(const f32x4*)(&arena[qrow * 68 + dt * 16 + quad * 4]);
        uint2 dd;
        dd.x = pk_bf16((o[qh2][dt][0] + a[0]) * inv, (o[qh2][dt][1] + a[1]) * inv);
        dd.y = pk_bf16((o[qh2][dt][2] + a[2]) * inv, (o[qh2][dt][3] + a[3]) * inv);
        *(uint2*)(ao + (size_t)(b * 2048 + sg) * 1024 + h * 64 + dt * 16 + quad * 4) = dd;
      }
    }
  }
}

extern "C" void kernel_launch(void* const* d_in, const int* in_sizes, int n_in,
                              void* d_out, int out_size, void* d_ws, size_t ws_size,
                              hipStream_t stream) {
  const float* x   = (const float*)d_in[0];
  const float* Wq  = (const float*)d_in[1];
  const float* Wk  = (const float*)d_in[2];
  const float* Wv  = (const float*)d_in[3];
  const float* Wff = (const float*)d_in[4];
  const float* bff = (const float*)d_in[5];
  float* out = (float*)d_out;

  uint16_t* ws = (uint16_t*)d_ws;
  uint16_t* x_bf   = ws;                 // 4M elems
  uint16_t* wq_bf  = ws + 4194304;       // 1M
  uint16_t* wk_bf  = ws + 5242880;       // 1M
  uint16_t* wv_bf  = ws + 6291456;       // 1M
  uint16_t* wff_bf = ws + 7340032;       // 1M
  uint16_t* q_bf   = ws + 8388608;       // 4M  (b,h,s,dh), pre-scaled by log2e/sqrt(D)
  uint16_t* k_bf   = ws + 12582912;      // 4M  (b,h,s,dh)
  uint16_t* vt_bf  = ws + 16777216;      // 4M  (b,h,dh,s)
  uint16_t* ao_bf  = ws + 20971520;      // 4M  (b,s,h*64+dh)

  cast_all<<<8192, 256, 0, stream>>>(x, Wq, Wk, Wv, Wff, x_bf, wq_bf, wk_bf, wv_bf, wff_bf);

  gemm_qkv<<<dim3(32, 8, 3), 256, 0, stream>>>(x_bf, wq_bf, wk_bf, wv_bf, q_bf, k_bf, vt_bf);
  attn<<<dim3(16, 32), 512, 0, stream>>>(q_bf, k_bf, vt_bf, ao_bf);
  gemm_ff<<<dim3(32, 16), 256, 0, stream>>>(ao_bf, wff_bf, bff, out);
}